// Round 7
// baseline (291.731 us; speedup 1.0000x reference)
//
#include <hip/hip_runtime.h>

// InnerShiftTriple: bz=4, c=512 (c2=256), h=w=64 (hw=4096), fp32 in/out, int32 mask.
// out = concat([former, latter, shifted]); shifted[i] = former[argmax_j sim(i,j)]
// for masked i over non-masked keys j, cosine sim of "latter" features.
// Argmax invariant to query normalization -> only keys normalized.
//
// Pass1: TQ=32 x 512-key items, static schedule; queries SGPR-broadcast;
// float2 key stream; 4 blocks/CU (launch_bounds(256,4); R3: (256,8) spills).
// R6 lesson: the remainder round was 58us for 9us of issue -- R4's q-split
// (8q items) has 32cyc issue per c-iter vs ~300cyc load latency: starved.
// THIS ROUND: remainder split along KEYS at wave granularity -- each wave
// owns a 32q x 128-key sub-item (identical per-wave FMA density to phase 1),
// no block barriers, wave-local shfl reduce, direct write to per-kq sub-slot.
// Same per-(q,key) fmaf chain over c; u64 max is exact -> bit-identical.
// Aux kernels (R6): LDS-staged gathers, unchanged this round.

#define HW 4096
#define C2 256
#define BZd 4
#define TQ 32         // queries per work item (SGPR-broadcast)
#define NK 2          // keys per thread (one float2)
#define BT 256        // pass1 block = 4 waves; block covers BT*NK = 512 keys
#define SLK 512       // keys per slice
#define NSL_MAX 8     // up to 8 slices of 512 keys
#define QT_MAX 128    // HW/TQ
#define P1_GRID 1024  // exactly the resident capacity at 4 blocks/CU

__device__ __forceinline__ unsigned ordf(float f) {
  unsigned u = __float_as_uint(f);
  return (u & 0x80000000u) ? ~u : (u | 0x80000000u);
}

__device__ __forceinline__ unsigned long long shfl_down_u64(unsigned long long v, int off) {
  unsigned lo = (unsigned)v, hi = (unsigned)(v >> 32);
  lo = __shfl_down(lo, off, 64);
  hi = __shfl_down(hi, off, 64);
  return ((unsigned long long)hi << 32) | lo;
}

// --- K1: inv-norm (blocks 0..255, 4x parallel over c-groups) + mask
//         compaction (blocks 256..259) ---------------------------------------
__global__ void prep_kernel(const float* __restrict__ in, const int* __restrict__ mask,
                            float* __restrict__ inv, int* __restrict__ qcnt,
                            int* __restrict__ kcnt, int* __restrict__ qlist,
                            int* __restrict__ klist, int* __restrict__ srcmap) {
  int bid = blockIdx.x, t = threadIdx.x;
  if (bid < 256) {
    // 64 pixels per block x 4 c-groups of 64 channels
    __shared__ float sred[4][64];
    int p = t & 63, g = t >> 6;
    int idx = bid * 64 + p;                   // [0, 16384); 64 | HW so no b-crossing
    int b = idx >> 12, j = idx & (HW - 1);
    const float* base = in + ((size_t)b * 512 + C2 + g * 64) * HW + j;
    float ss = 0.f;
#pragma unroll 8
    for (int c = 0; c < 64; ++c) { float v = base[(size_t)c * HW]; ss = fmaf(v, v, ss); }
    sred[g][p] = ss;
    __syncthreads();
    if (g == 0) {
      float s0 = ((sred[0][p] + sred[1][p]) + sred[2][p]) + sred[3][p];
      inv[idx] = 1.0f / (sqrtf(s0) + 1e-8f);
    }
  } else {
    int b = bid - 256;
    __shared__ int s[256];
    const int* m = mask + b * HW;
    int base = t * 16;
    int fl = 0, cq = 0;
#pragma unroll
    for (int i = 0; i < 16; ++i) { int f = (m[base + i] >= 1); fl |= f << i; cq += f; }
    s[t] = cq; __syncthreads();
    for (int off = 1; off < 256; off <<= 1) {
      int v = (t >= off) ? s[t - off] : 0;
      __syncthreads(); s[t] += v; __syncthreads();
    }
    int total = s[255];
    int qp = s[t] - cq;
    int kp = base - qp;
    for (int i = 0; i < 16; ++i) {
      int j = base + i;
      if ((fl >> i) & 1) qlist[b * HW + qp++] = j;
      else               klist[b * HW + kp++] = j;
      srcmap[b * HW + j] = -1;
    }
    if (t == 0) { qcnt[b] = total; kcnt[b] = HW - total; }
  }
}

// --- K2: pack normalized keys + un-normalized queries via LDS-staged gather.
__global__ void pack_kernel(const float* __restrict__ in, const float* __restrict__ inv,
                            const int* __restrict__ qcnt, const int* __restrict__ kcnt,
                            const int* __restrict__ qlist, const int* __restrict__ klist,
                            float* __restrict__ kpack, float* __restrict__ qpack) {
  __shared__ float slat[HW];   // 16 KB
  __shared__ float sinv[HW];   // 16 KB
  int t = threadIdx.x;
  int c = blockIdx.x, b = blockIdx.y;
  const float4* lat4 = (const float4*)(in + ((size_t)b * 512 + C2 + c) * HW);
  const float4* inv4 = (const float4*)(inv + (size_t)b * HW);
#pragma unroll
  for (int i = 0; i < 4; ++i) {
    int p = i * 256 + t;
    ((float4*)slat)[p] = lat4[p];
    ((float4*)sinv)[p] = inv4[p];
  }
  int kc = kcnt[b], nq = qcnt[b];
  const int* kl = klist + b * HW;
  const int* ql = qlist + b * HW;
  float* kdst = kpack + (size_t)(b * C2 + c) * HW;
  float* qdst = qpack + (size_t)(b * C2 + c) * HW;
  __syncthreads();
#pragma unroll
  for (int i = 0; i < 4; ++i) {
    int jj = (i * 256 + t) * 4;
    int4 k4 = *(const int4*)(kl + jj);   // entries beyond kc are garbage: guarded
    int4 q4 = *(const int4*)(ql + jj);
    float4 kv, qv;
    kv.x = (jj + 0 < kc) ? slat[k4.x] * sinv[k4.x] : 0.f;
    kv.y = (jj + 1 < kc) ? slat[k4.y] * sinv[k4.y] : 0.f;
    kv.z = (jj + 2 < kc) ? slat[k4.z] * sinv[k4.z] : 0.f;
    kv.w = (jj + 3 < kc) ? slat[k4.w] * sinv[k4.w] : 0.f;
    qv.x = (jj + 0 < nq) ? slat[q4.x] : 0.f;
    qv.y = (jj + 1 < nq) ? slat[q4.y] : 0.f;
    qv.z = (jj + 2 < nq) ? slat[q4.z] : 0.f;
    qv.w = (jj + 3 < nq) ? slat[q4.w] : 0.f;
    *(float4*)(kdst + jj) = kv;
    *(float4*)(qdst + jj) = qv;
  }
}

// --- K3 helpers --------------------------------------------------------------
__device__ __forceinline__ void decode_id(unsigned idx,
    int nt0, int nt1, int nt2,
    int q0, int q1, int q2, int q3,
    int k0c, int k1c, int k2c, int k3c,
    int& b, int& sl, int& qtile, int& kc) {
  int qtn;
  b = 0; qtn = q0; kc = k0c;
  if (idx >= (unsigned)nt0) {
    idx -= nt0; b = 1; qtn = q1; kc = k1c;
    if (idx >= (unsigned)nt1) {
      idx -= nt1; b = 2; qtn = q2; kc = k2c;
      if (idx >= (unsigned)nt2) { idx -= nt2; b = 3; qtn = q3; kc = k3c; }
    }
  }
  sl = (int)(idx / (unsigned)qtn);
  qtile = (int)(idx - (unsigned)sl * (unsigned)qtn);
}

// Full item (phase 1): 32q x 512k on a 4-wave block; writes kq sub-slot 0.
__device__ __forceinline__ void run_item(
    const float* __restrict__ qpack, const float* __restrict__ kpack,
    unsigned long long* __restrict__ partials,
    unsigned long long (*red)[TQ],
    int b, int sl, int qtile, int kc,
    int t, int lane, int wid) {
  int qstart = qtile << 5;
  int kbase = (sl << 9) + (t << 1);   // this thread's 2 keys

  const float* qb = qpack + ((size_t)b * C2) * HW + qstart;
  const float* kcol = kpack + ((size_t)b * C2) * HW + kbase;

  float acc[NK][TQ];
#pragma unroll
  for (int r = 0; r < NK; ++r)
#pragma unroll
    for (int q = 0; q < TQ; ++q) acc[r][q] = 0.f;

  float2 k0 = *(const float2*)(kcol);
  float2 k1 = *(const float2*)(kcol + HW);
#pragma unroll 2
  for (int c = 0; c < C2; ++c) {
    float2 kq = k0;
    k0 = k1;
    int cp = c + 2; if (cp > C2 - 1) cp = C2 - 1;
    k1 = *(const float2*)(kcol + (size_t)cp * HW);
    float kv[NK] = {kq.x, kq.y};
    const float* qc_ = qb + (size_t)c * HW;   // uniform address
#pragma unroll
    for (int i = 0; i < TQ; ++i) {
      float qv = qc_[i];                       // s_load -> SGPR
#pragma unroll
      for (int r = 0; r < NK; ++r)
        acc[r][i] = fmaf(kv[r], qv, acc[r][i]);
    }
  }

#pragma unroll
  for (int q = 0; q < TQ; ++q) {
    unsigned long long v = 0ull;
#pragma unroll
    for (int r = 0; r < NK; ++r) {
      int kk = kbase + r;
      if (kk < kc) {
        unsigned long long pk =
            ((unsigned long long)ordf(acc[r][q]) << 32) | (unsigned)(0xFFFFFFFFu - (unsigned)kk);
        if (pk > v) v = pk;
      }
    }
#pragma unroll
    for (int off = 32; off >= 1; off >>= 1) {
      unsigned long long o = shfl_down_u64(v, off);
      if (o > v) v = o;
    }
    if (lane == 0) red[wid][q] = v;
  }
  __syncthreads();
  if (t < TQ) {
    unsigned long long v = red[0][t];
#pragma unroll
    for (int ww = 1; ww < 4; ++ww) if (red[ww][t] > v) v = red[ww][t];
    partials[((((size_t)b * NSL_MAX + sl) * 4 + 0) * QT_MAX + qtile) * TQ + t] = v;
  }
  __syncthreads();
}

// Sub-item (phase 2): one WAVE owns 32q x 128 keys (quarter kq of the slice).
// Same per-wave FMA density as phase 1; wave-local reduce; no barriers.
__device__ __forceinline__ void run_subitem(
    const float* __restrict__ qpack, const float* __restrict__ kpack,
    unsigned long long* __restrict__ partials,
    int b, int sl, int qtile, int kq, int kc, int lane) {
  int qstart = qtile << 5;
  int kbase = (sl << 9) + (kq << 7) + (lane << 1);

  const float* qb = qpack + ((size_t)b * C2) * HW + qstart;
  const float* kcol = kpack + ((size_t)b * C2) * HW + kbase;

  float acc[NK][TQ];
#pragma unroll
  for (int r = 0; r < NK; ++r)
#pragma unroll
    for (int q = 0; q < TQ; ++q) acc[r][q] = 0.f;

  float2 k0 = *(const float2*)(kcol);
  float2 k1 = *(const float2*)(kcol + HW);
#pragma unroll 2
  for (int c = 0; c < C2; ++c) {
    float2 kqv = k0;
    k0 = k1;
    int cp = c + 2; if (cp > C2 - 1) cp = C2 - 1;
    k1 = *(const float2*)(kcol + (size_t)cp * HW);
    float kv[NK] = {kqv.x, kqv.y};
    const float* qc_ = qb + (size_t)c * HW;   // uniform address
#pragma unroll
    for (int i = 0; i < TQ; ++i) {
      float qv = qc_[i];                       // s_load -> SGPR
#pragma unroll
      for (int r = 0; r < NK; ++r)
        acc[r][i] = fmaf(kv[r], qv, acc[r][i]);
    }
  }

#pragma unroll
  for (int q = 0; q < TQ; ++q) {
    unsigned long long v = 0ull;
#pragma unroll
    for (int r = 0; r < NK; ++r) {
      int kk = kbase + r;
      if (kk < kc) {
        unsigned long long pk =
            ((unsigned long long)ordf(acc[r][q]) << 32) | (unsigned)(0xFFFFFFFFu - (unsigned)kk);
        if (pk > v) v = pk;
      }
    }
#pragma unroll
    for (int off = 32; off >= 1; off >>= 1) {
      unsigned long long o = shfl_down_u64(v, off);
      if (o > v) v = o;
    }
    if (lane == 0)
      partials[((((size_t)b * NSL_MAX + sl) * 4 + kq) * QT_MAX + qtile) * TQ + q] = v;
  }
}

// --- K3: fused GEMM + per-slice argmax over dense (b,sl,qtile) work items ----
__global__ __launch_bounds__(BT, 4) void argmax_pass1(
    const float* __restrict__ qpack, const float* __restrict__ kpack,
    const int* __restrict__ qcnt, const int* __restrict__ kcnt,
    unsigned long long* __restrict__ partials) {
  int k0c = kcnt[0], k1c = kcnt[1], k2c = kcnt[2], k3c = kcnt[3];
  int s0 = (k0c + SLK - 1) >> 9, s1 = (k1c + SLK - 1) >> 9;
  int s2 = (k2c + SLK - 1) >> 9, s3 = (k3c + SLK - 1) >> 9;
  int q0 = (qcnt[0] + TQ - 1) >> 5, q1 = (qcnt[1] + TQ - 1) >> 5;
  int q2 = (qcnt[2] + TQ - 1) >> 5, q3 = (qcnt[3] + TQ - 1) >> 5;
  int nt0 = q0 * s0, nt1 = q1 * s1, nt2 = q2 * s2, nt3 = q3 * s3;
  unsigned total = (unsigned)(nt0 + nt1 + nt2 + nt3);
  unsigned S = gridDim.x;
  unsigned F = total / S;
  unsigned fullN = F * S;
  unsigned R = total - fullN;

  int t = threadIdx.x;
  int lane = t & 63, wid = t >> 6;
  __shared__ unsigned long long red[4][TQ];

  // phase 1: full-size items (all S slots busy for F rounds)
  for (unsigned w = blockIdx.x; w < fullN; w += S) {
    int b, sl, qtile, kc;
    decode_id(w, nt0, nt1, nt2, q0, q1, q2, q3, k0c, k1c, k2c, k3c, b, sl, qtile, kc);
    run_item(qpack, kpack, partials, red, b, sl, qtile, kc, t, lane, wid);
  }
  // phase 2: remainder at WAVE granularity: sub-item = 32q x 128 keys.
  // No block barriers; each wave independent.
  for (unsigned gw = blockIdx.x * 4u + (unsigned)wid; gw < 4u * R; gw += 4u * S) {
    unsigned id = fullN + (gw >> 2);
    int kq = (int)(gw & 3u);
    int b, sl, qtile, kc;
    decode_id(id, nt0, nt1, nt2, q0, q1, q2, q3, k0c, k1c, k2c, k3c, b, sl, qtile, kc);
    run_subitem(qpack, kpack, partials, b, sl, qtile, kq, kc, lane);
  }
}

// --- K4: reduce slices -> srcmap. Recomputes the phase split: phase-1 ids
// have only kq sub-slot 0 written; remainder ids have all 4. ----------------
__global__ void argmax_pass2(const unsigned long long* __restrict__ partials,
                             const int* __restrict__ qcnt, const int* __restrict__ kcnt,
                             const int* __restrict__ qlist, const int* __restrict__ klist,
                             int* __restrict__ srcmap) {
  int idx = blockIdx.x * 256 + threadIdx.x;  // [0, 16384)
  int b = idx >> 12, qpos = idx & (HW - 1);
  if (qpos >= qcnt[b]) return;

  int k0c = kcnt[0], k1c = kcnt[1], k2c = kcnt[2], k3c = kcnt[3];
  int s0 = (k0c + SLK - 1) >> 9, s1 = (k1c + SLK - 1) >> 9;
  int s2 = (k2c + SLK - 1) >> 9, s3 = (k3c + SLK - 1) >> 9;
  int q0 = (qcnt[0] + TQ - 1) >> 5, q1 = (qcnt[1] + TQ - 1) >> 5;
  int q2 = (qcnt[2] + TQ - 1) >> 5, q3 = (qcnt[3] + TQ - 1) >> 5;
  int nt0 = q0 * s0, nt1 = q1 * s1, nt2 = q2 * s2, nt3 = q3 * s3;
  unsigned total = (unsigned)(nt0 + nt1 + nt2 + nt3);
  unsigned F = total / P1_GRID;
  unsigned fullN = F * P1_GRID;

  int kc = kcnt[b];
  int ns = (kc + SLK - 1) >> 9;
  int qtn = (b == 0) ? q0 : (b == 1) ? q1 : (b == 2) ? q2 : q3;
  int base = (b == 0) ? 0 : (b == 1) ? nt0 : (b == 2) ? (nt0 + nt1) : (nt0 + nt1 + nt2);
  int qtile = qpos >> 5, q = qpos & (TQ - 1);

  unsigned long long v = 0ull;
  for (int s = 0; s < ns; ++s) {
    unsigned w = (unsigned)(base + s * qtn + qtile);
    size_t pb = (((size_t)b * NSL_MAX + s) * 4) * QT_MAX;
    if (w < fullN) {
      unsigned long long p = partials[(pb + qtile) * TQ + q];
      if (p > v) v = p;
    } else {
#pragma unroll
      for (int kq = 0; kq < 4; ++kq) {
        unsigned long long p = partials[(pb + (size_t)kq * QT_MAX + qtile) * TQ + q];
        if (p > v) v = p;
      }
    }
  }
  if (!v) return;
  int kk = (int)(0xFFFFFFFFu - (unsigned)(v & 0xFFFFFFFFull));
  srcmap[b * HW + qlist[b * HW + qpos]] = klist[b * HW + kk];
}

// --- K5: one block per (b,c) plane: coalesced row load -> LDS; passthrough
// write; for c<256 the same LDS row serves the shifted gather (lds[s]) --------
__global__ void out_kernel(const float* __restrict__ in, const int* __restrict__ srcmap,
                           float* __restrict__ out) {
  __shared__ float srow[HW];   // 16 KB
  int bid = blockIdx.x;
  int b = bid >> 9, c = bid & 511;
  int t = threadIdx.x;
  const float4* src = (const float4*)(in + ((size_t)b * 512 + c) * HW);
  float4* dst = (float4*)(out + ((size_t)b * 768 + c) * HW);
#pragma unroll
  for (int i = 0; i < 4; ++i) {
    int p = i * 256 + t;
    float4 v = src[p];
    ((float4*)srow)[p] = v;
    dst[p] = v;
  }
  if (c < 256) {
    __syncthreads();
    const int* sm = srcmap + b * HW;
    float4* dst2 = (float4*)(out + ((size_t)b * 768 + 512 + c) * HW);
#pragma unroll
    for (int i = 0; i < 4; ++i) {
      int p = i * 256 + t;
      int j0 = p * 4;
      int4 s4 = *(const int4*)(sm + j0);
      float4 o;
      o.x = (s4.x >= 0) ? srow[s4.x] : 0.f;
      o.y = (s4.y >= 0) ? srow[s4.y] : 0.f;
      o.z = (s4.z >= 0) ? srow[s4.z] : 0.f;
      o.w = (s4.w >= 0) ? srow[s4.w] : 0.f;
      dst2[p] = o;
    }
  }
}

extern "C" void kernel_launch(void* const* d_in, const int* in_sizes, int n_in,
                              void* d_out, int out_size, void* d_ws, size_t ws_size,
                              hipStream_t stream) {
  const float* in = (const float*)d_in[0];
  const int* mask = (const int*)d_in[1];
  float* out = (float*)d_out;

  // workspace layout (~38 MB)
  unsigned long long* partials = (unsigned long long*)d_ws;                      // 4*8*4*128*32 u64 = 4 MB
  float* kpack = (float*)(partials + (size_t)BZd * NSL_MAX * 4 * QT_MAX * TQ);   // 16.8 MB
  float* qpack = kpack + (size_t)BZd * C2 * HW;                                   // 16.8 MB
  float* inv = qpack + (size_t)BZd * C2 * HW;                                     // 64 KB
  int* qlist = (int*)(inv + BZd * HW);                                            // 64 KB
  int* klist = qlist + BZd * HW;                                                  // 64 KB
  int* srcmap = klist + BZd * HW;                                                 // 64 KB
  int* qcnt = srcmap + BZd * HW;                                                  // 16 B
  int* kcnt = qcnt + BZd;                                                         // 16 B

  hipLaunchKernelGGL(prep_kernel, dim3(256 + BZd), dim3(256), 0, stream,
                     in, mask, inv, qcnt, kcnt, qlist, klist, srcmap);
  hipLaunchKernelGGL(pack_kernel, dim3(C2, BZd), dim3(256), 0, stream,
                     in, inv, qcnt, kcnt, qlist, klist, kpack, qpack);
  hipLaunchKernelGGL(argmax_pass1, dim3(P1_GRID), dim3(BT), 0, stream,
                     qpack, kpack, qcnt, kcnt, partials);
  hipLaunchKernelGGL(argmax_pass2, dim3(BZd * HW / 256), dim3(256), 0, stream,
                     partials, qcnt, kcnt, qlist, klist, srcmap);
  hipLaunchKernelGGL(out_kernel, dim3(BZd * 512), dim3(256), 0, stream,
                     in, srcmap, out);
}

// Round 8
// 223.672 us; speedup vs baseline: 1.3043x; 1.3043x over previous
//
#include <hip/hip_runtime.h>

// InnerShiftTriple: bz=4, c=512 (c2=256), h=w=64 (hw=4096), fp32 in/out, int32 mask.
// out = concat([former, latter, shifted]); shifted[i] = former[argmax_j sim(i,j)]
// for masked i over non-masked keys j, cosine sim of "latter" features.
// Argmax invariant to query normalization -> only keys normalized.
//
// Pass1 structure = R6 known-good (228us total): TQ=32 x 512-key items, 4-wave
// blocks, launch_bounds(256,4), static schedule + q-split remainder via the
// SAME run_item template (R7 lesson: a second inner-loop instantiation bloats
// V+AGPR -> occupancy 22%, 188us; reverted).
// THIS ROUND:
//  (a) v_pk_fma_f32: acc as float2 pairs over q, __builtin_elementwise_fma on
//      2-vectors -> packed fp32 FMA halves issue cycles in the issue-bound
//      steady state (55us floor -> 27us). Per-element IEEE fma, same c order
//      -> bit-identical argmax. If backend doesn't emit packed: neutral.
//  (b) passthrough copy (out[.., 0:512] = in, 128MB, srcmap-independent) runs
//      as 2048 extra blocks appended to pass1's grid: in-order dispatch puts
//      them in the slots freed during the latency-bound remainder tail ->
//      copy is free; out_kernel becomes gather-only (~15us).
//      NOTE: pass1 WRITE_SIZE ~130MB is the fused copy, NOT spill (spill
//      signature = R3: 680MB + VGPR drop + 5x dur).

#define HW 4096
#define C2 256
#define BZd 4
#define TQ 32         // queries per full work item (SGPR-broadcast)
#define NK 2          // keys per thread (one float2)
#define BT 256        // pass1 block = 4 waves; block covers BT*NK = 512 keys
#define SLK 512       // keys per slice
#define NSL_MAX 8     // up to 8 slices of 512 keys
#define QT_MAX 128    // HW/TQ
#define P1_GRID 1024  // exactly the resident capacity at 4 blocks/CU
#define CP_GRID 2048  // appended passthrough-copy blocks (BZd*512 planes)

typedef float v2f __attribute__((ext_vector_type(2)));

__device__ __forceinline__ unsigned ordf(float f) {
  unsigned u = __float_as_uint(f);
  return (u & 0x80000000u) ? ~u : (u | 0x80000000u);
}

__device__ __forceinline__ unsigned long long shfl_down_u64(unsigned long long v, int off) {
  unsigned lo = (unsigned)v, hi = (unsigned)(v >> 32);
  lo = __shfl_down(lo, off, 64);
  hi = __shfl_down(hi, off, 64);
  return ((unsigned long long)hi << 32) | lo;
}

// --- K1: inv-norm (blocks 0..255, 4x parallel over c-groups) + mask
//         compaction (blocks 256..259) ---------------------------------------
__global__ void prep_kernel(const float* __restrict__ in, const int* __restrict__ mask,
                            float* __restrict__ inv, int* __restrict__ qcnt,
                            int* __restrict__ kcnt, int* __restrict__ qlist,
                            int* __restrict__ klist, int* __restrict__ srcmap) {
  int bid = blockIdx.x, t = threadIdx.x;
  if (bid < 256) {
    // 64 pixels per block x 4 c-groups of 64 channels
    __shared__ float sred[4][64];
    int p = t & 63, g = t >> 6;
    int idx = bid * 64 + p;                   // [0, 16384); 64 | HW so no b-crossing
    int b = idx >> 12, j = idx & (HW - 1);
    const float* base = in + ((size_t)b * 512 + C2 + g * 64) * HW + j;
    float ss = 0.f;
#pragma unroll 8
    for (int c = 0; c < 64; ++c) { float v = base[(size_t)c * HW]; ss = fmaf(v, v, ss); }
    sred[g][p] = ss;
    __syncthreads();
    if (g == 0) {
      float s0 = ((sred[0][p] + sred[1][p]) + sred[2][p]) + sred[3][p];
      inv[idx] = 1.0f / (sqrtf(s0) + 1e-8f);
    }
  } else {
    int b = bid - 256;
    __shared__ int s[256];
    const int* m = mask + b * HW;
    int base = t * 16;
    int fl = 0, cq = 0;
#pragma unroll
    for (int i = 0; i < 16; ++i) { int f = (m[base + i] >= 1); fl |= f << i; cq += f; }
    s[t] = cq; __syncthreads();
    for (int off = 1; off < 256; off <<= 1) {
      int v = (t >= off) ? s[t - off] : 0;
      __syncthreads(); s[t] += v; __syncthreads();
    }
    int total = s[255];
    int qp = s[t] - cq;
    int kp = base - qp;
    for (int i = 0; i < 16; ++i) {
      int j = base + i;
      if ((fl >> i) & 1) qlist[b * HW + qp++] = j;
      else               klist[b * HW + kp++] = j;
      srcmap[b * HW + j] = -1;
    }
    if (t == 0) { qcnt[b] = total; kcnt[b] = HW - total; }
  }
}

// --- K2: pack normalized keys + un-normalized queries via LDS-staged gather.
__global__ void pack_kernel(const float* __restrict__ in, const float* __restrict__ inv,
                            const int* __restrict__ qcnt, const int* __restrict__ kcnt,
                            const int* __restrict__ qlist, const int* __restrict__ klist,
                            float* __restrict__ kpack, float* __restrict__ qpack) {
  __shared__ float slat[HW];   // 16 KB
  __shared__ float sinv[HW];   // 16 KB
  int t = threadIdx.x;
  int c = blockIdx.x, b = blockIdx.y;
  const float4* lat4 = (const float4*)(in + ((size_t)b * 512 + C2 + c) * HW);
  const float4* inv4 = (const float4*)(inv + (size_t)b * HW);
#pragma unroll
  for (int i = 0; i < 4; ++i) {
    int p = i * 256 + t;
    ((float4*)slat)[p] = lat4[p];
    ((float4*)sinv)[p] = inv4[p];
  }
  int kc = kcnt[b], nq = qcnt[b];
  const int* kl = klist + b * HW;
  const int* ql = qlist + b * HW;
  float* kdst = kpack + (size_t)(b * C2 + c) * HW;
  float* qdst = qpack + (size_t)(b * C2 + c) * HW;
  __syncthreads();
#pragma unroll
  for (int i = 0; i < 4; ++i) {
    int jj = (i * 256 + t) * 4;
    int4 k4 = *(const int4*)(kl + jj);   // entries beyond kc are garbage: guarded
    int4 q4 = *(const int4*)(ql + jj);
    float4 kv, qv;
    kv.x = (jj + 0 < kc) ? slat[k4.x] * sinv[k4.x] : 0.f;
    kv.y = (jj + 1 < kc) ? slat[k4.y] * sinv[k4.y] : 0.f;
    kv.z = (jj + 2 < kc) ? slat[k4.z] * sinv[k4.z] : 0.f;
    kv.w = (jj + 3 < kc) ? slat[k4.w] * sinv[k4.w] : 0.f;
    qv.x = (jj + 0 < nq) ? slat[q4.x] : 0.f;
    qv.y = (jj + 1 < nq) ? slat[q4.y] : 0.f;
    qv.z = (jj + 2 < nq) ? slat[q4.z] : 0.f;
    qv.w = (jj + 3 < nq) ? slat[q4.w] : 0.f;
    *(float4*)(kdst + jj) = kv;
    *(float4*)(qdst + jj) = qv;
  }
}

// --- K3 helpers --------------------------------------------------------------
__device__ __forceinline__ void decode_id(unsigned idx,
    int nt0, int nt1, int nt2,
    int q0, int q1, int q2, int q3,
    int k0c, int k1c, int k2c, int k3c,
    int& b, int& sl, int& qtile, int& kc) {
  int qtn;
  b = 0; qtn = q0; kc = k0c;
  if (idx >= (unsigned)nt0) {
    idx -= nt0; b = 1; qtn = q1; kc = k1c;
    if (idx >= (unsigned)nt1) {
      idx -= nt1; b = 2; qtn = q2; kc = k2c;
      if (idx >= (unsigned)nt2) { idx -= nt2; b = 3; qtn = q3; kc = k3c; }
    }
  }
  sl = (int)(idx / (unsigned)qtn);
  qtile = (int)(idx - (unsigned)sl * (unsigned)qtn);
}

// One work item: TQL queries (qtile*32 + qoff ..) x one 512-key slice.
// acc held as q-pairs (v2f); __builtin_elementwise_fma on 2-vectors selects
// v_pk_fma_f32. Per-element IEEE fma in the same c order -> bit-exact vs
// the scalar fmaf chain of earlier rounds.
template <int TQL>
__device__ __forceinline__ void run_item(
    const float* __restrict__ qpack, const float* __restrict__ kpack,
    unsigned long long* __restrict__ partials,
    unsigned long long (*red)[TQ],
    int b, int sl, int qtile, int qoff, int kc,
    int t, int lane, int wid) {
  int qstart = (qtile << 5) + qoff;
  int kbase = (sl << 9) + (t << 1);   // this thread's 2 keys

  // wave-uniform query base -> scalar loads (SGPR broadcast operands)
  const float* qb = qpack + ((size_t)b * C2) * HW + qstart;
  const float* kcol = kpack + ((size_t)b * C2) * HW + kbase;

  v2f acc[NK][TQL / 2];
#pragma unroll
  for (int r = 0; r < NK; ++r)
#pragma unroll
    for (int q = 0; q < TQL / 2; ++q) acc[r][q] = (v2f){0.f, 0.f};

  // rotating depth-2 prefetch of the key float2 (stride HW floats per c)
  float2 k0 = *(const float2*)(kcol);
  float2 k1 = *(const float2*)(kcol + HW);
#pragma unroll 2
  for (int c = 0; c < C2; ++c) {
    float2 kq = k0;
    k0 = k1;
    int cp = c + 2; if (cp > C2 - 1) cp = C2 - 1;
    k1 = *(const float2*)(kcol + (size_t)cp * HW);
    v2f kv2[NK];
    kv2[0] = (v2f){kq.x, kq.x};
    kv2[1] = (v2f){kq.y, kq.y};
    const v2f* qc2 = (const v2f*)(qb + (size_t)c * HW);   // uniform address
#pragma unroll
    for (int i = 0; i < TQL / 2; ++i) {
      v2f qv = qc2[i];                        // s_load pair -> SGPR
#pragma unroll
      for (int r = 0; r < NK; ++r)
        acc[r][i] = __builtin_elementwise_fma(kv2[r], qv, acc[r][i]);
    }
  }

  // per-q reduction: wave shfl, then cross-wave via LDS
#pragma unroll
  for (int q = 0; q < TQL; ++q) {
    unsigned long long v = 0ull;
#pragma unroll
    for (int r = 0; r < NK; ++r) {
      int kk = kbase + r;
      if (kk < kc) {
        float a = (q & 1) ? acc[r][q >> 1].y : acc[r][q >> 1].x;
        unsigned long long pk =
            ((unsigned long long)ordf(a) << 32) | (unsigned)(0xFFFFFFFFu - (unsigned)kk);
        if (pk > v) v = pk;
      }
    }
#pragma unroll
    for (int off = 32; off >= 1; off >>= 1) {
      unsigned long long o = shfl_down_u64(v, off);
      if (o > v) v = o;
    }
    if (lane == 0) red[wid][q] = v;
  }
  __syncthreads();
  if (t < TQL) {
    unsigned long long v = red[0][t];
#pragma unroll
    for (int ww = 1; ww < 4; ++ww) if (red[ww][t] > v) v = red[ww][t];
    partials[(((size_t)b * NSL_MAX + sl) * QT_MAX + qtile) * TQ + qoff + t] = v;
  }
  __syncthreads();
}

// --- K3: fused GEMM + per-slice argmax over dense (b,sl,qtile) work items,
// plus appended passthrough-copy blocks (fill the remainder-tail slots) ------
__global__ __launch_bounds__(BT, 4) void argmax_pass1(
    const float* __restrict__ qpack, const float* __restrict__ kpack,
    const int* __restrict__ qcnt, const int* __restrict__ kcnt,
    unsigned long long* __restrict__ partials,
    const float* __restrict__ in, float* __restrict__ out) {
  int t = threadIdx.x;
  if (blockIdx.x >= P1_GRID) {
    // passthrough copy: one (b,c) plane per block, c in [0,512)
    int bid2 = blockIdx.x - P1_GRID;
    int b = bid2 >> 9, c = bid2 & 511;
    const float4* src = (const float4*)(in + ((size_t)b * 512 + c) * HW);
    float4* dst = (float4*)(out + ((size_t)b * 768 + c) * HW);
#pragma unroll
    for (int i = 0; i < 4; ++i) dst[i * 256 + t] = src[i * 256 + t];
    return;
  }

  // per-batch work-item counts (uniform -> scalar)
  int k0c = kcnt[0], k1c = kcnt[1], k2c = kcnt[2], k3c = kcnt[3];
  int s0 = (k0c + SLK - 1) >> 9, s1 = (k1c + SLK - 1) >> 9;
  int s2 = (k2c + SLK - 1) >> 9, s3 = (k3c + SLK - 1) >> 9;
  int q0 = (qcnt[0] + TQ - 1) >> 5, q1 = (qcnt[1] + TQ - 1) >> 5;
  int q2 = (qcnt[2] + TQ - 1) >> 5, q3 = (qcnt[3] + TQ - 1) >> 5;
  int nt0 = q0 * s0, nt1 = q1 * s1, nt2 = q2 * s2, nt3 = q3 * s3;
  unsigned total = (unsigned)(nt0 + nt1 + nt2 + nt3);
  unsigned S = P1_GRID;
  unsigned F = total / S;
  unsigned fullN = F * S;
  unsigned R = total - fullN;

  int lane = t & 63, wid = t >> 6;
  __shared__ unsigned long long red[4][TQ];

  // phase 1: full-size items (all S slots busy for F rounds)
  for (unsigned w = blockIdx.x; w < fullN; w += S) {
    int b, sl, qtile, kc;
    decode_id(w, nt0, nt1, nt2, q0, q1, q2, q3, k0c, k1c, k2c, k3c, b, sl, qtile, kc);
    run_item<TQ>(qpack, kpack, partials, red, b, sl, qtile, 0, kc, t, lane, wid);
  }
  // phase 2: remainder items split 4-ways along q (quarter-duration round)
  for (unsigned qi = blockIdx.x; qi < 4u * R; qi += S) {
    unsigned id = fullN + (qi >> 2);
    int sub = (int)(qi & 3u);
    int b, sl, qtile, kc;
    decode_id(id, nt0, nt1, nt2, q0, q1, q2, q3, k0c, k1c, k2c, k3c, b, sl, qtile, kc);
    run_item<8>(qpack, kpack, partials, red, b, sl, qtile, sub * 8, kc, t, lane, wid);
  }
}

// --- K4: reduce slices -> srcmap --------------------------------------------
__global__ void argmax_pass2(const unsigned long long* __restrict__ partials,
                             const int* __restrict__ qcnt, const int* __restrict__ kcnt,
                             const int* __restrict__ qlist, const int* __restrict__ klist,
                             int* __restrict__ srcmap) {
  int idx = blockIdx.x * 256 + threadIdx.x;  // [0, 16384)
  int b = idx >> 12, qpos = idx & (HW - 1);
  if (qpos >= qcnt[b]) return;
  int kc = kcnt[b];
  int ns = (kc + SLK - 1) >> 9;
  int qtile = qpos >> 5, q = qpos & (TQ - 1);
  unsigned long long v = 0ull;
  for (int s = 0; s < ns; ++s) {
    unsigned long long p = partials[(((size_t)b * NSL_MAX + s) * QT_MAX + qtile) * TQ + q];
    if (p > v) v = p;
  }
  if (!v) return;
  int kk = (int)(0xFFFFFFFFu - (unsigned)(v & 0xFFFFFFFFull));
  srcmap[b * HW + qlist[b * HW + qpos]] = klist[b * HW + kk];
}

// --- K5: gather-only: one block per (b,c<256): stage former plane in LDS,
// gather via srcmap (passthrough already written by pass1's copy blocks) ------
__global__ void out_kernel(const float* __restrict__ in, const int* __restrict__ srcmap,
                           float* __restrict__ out) {
  __shared__ float srow[HW];   // 16 KB
  int bid = blockIdx.x;
  int b = bid >> 8, c = bid & 255;
  int t = threadIdx.x;
  const float4* src = (const float4*)(in + ((size_t)b * 512 + c) * HW);
#pragma unroll
  for (int i = 0; i < 4; ++i) ((float4*)srow)[i * 256 + t] = src[i * 256 + t];
  __syncthreads();
  const int* sm = srcmap + b * HW;
  float4* dst2 = (float4*)(out + ((size_t)b * 768 + 512 + c) * HW);
#pragma unroll
  for (int i = 0; i < 4; ++i) {
    int p = i * 256 + t;
    int j0 = p * 4;
    int4 s4 = *(const int4*)(sm + j0);
    float4 o;
    o.x = (s4.x >= 0) ? srow[s4.x] : 0.f;
    o.y = (s4.y >= 0) ? srow[s4.y] : 0.f;
    o.z = (s4.z >= 0) ? srow[s4.z] : 0.f;
    o.w = (s4.w >= 0) ? srow[s4.w] : 0.f;
    dst2[p] = o;
  }
}

extern "C" void kernel_launch(void* const* d_in, const int* in_sizes, int n_in,
                              void* d_out, int out_size, void* d_ws, size_t ws_size,
                              hipStream_t stream) {
  const float* in = (const float*)d_in[0];
  const int* mask = (const int*)d_in[1];
  float* out = (float*)d_out;

  // workspace layout (~35 MB)
  unsigned long long* partials = (unsigned long long*)d_ws;                    // 4*8*128*32 u64 = 1 MB
  float* kpack = (float*)(partials + (size_t)BZd * NSL_MAX * QT_MAX * TQ);     // 16.8 MB
  float* qpack = kpack + (size_t)BZd * C2 * HW;                                 // 16.8 MB
  float* inv = qpack + (size_t)BZd * C2 * HW;                                   // 64 KB
  int* qlist = (int*)(inv + BZd * HW);                                          // 64 KB
  int* klist = qlist + BZd * HW;                                                // 64 KB
  int* srcmap = klist + BZd * HW;                                               // 64 KB
  int* qcnt = srcmap + BZd * HW;                                                // 16 B
  int* kcnt = qcnt + BZd;                                                       // 16 B

  hipLaunchKernelGGL(prep_kernel, dim3(256 + BZd), dim3(256), 0, stream,
                     in, mask, inv, qcnt, kcnt, qlist, klist, srcmap);
  hipLaunchKernelGGL(pack_kernel, dim3(C2, BZd), dim3(256), 0, stream,
                     in, inv, qcnt, kcnt, qlist, klist, kpack, qpack);
  hipLaunchKernelGGL(argmax_pass1, dim3(P1_GRID + CP_GRID), dim3(BT), 0, stream,
                     qpack, kpack, qcnt, kcnt, partials, in, out);
  hipLaunchKernelGGL(argmax_pass2, dim3(BZd * HW / 256), dim3(256), 0, stream,
                     partials, qcnt, kcnt, qlist, klist, srcmap);
  hipLaunchKernelGGL(out_kernel, dim3(BZd * 256), dim3(256), 0, stream,
                     in, srcmap, out);
}